// Round 2
// baseline (88962.396 us; speedup 1.0000x reference)
//
#include <hip/hip_runtime.h>

// Problem constants
#define BB 64       // batch
#define TT 512      // time steps
#define II 128      // input dim
#define HH 512      // hidden
#define CC 5        // out classes

// ---------------------------------------------------------------------------
// GEMM: out[m][n] = sum_k A[m][k] * W[n][k] + b1[n] + b2[n]
// M = 32768 (grid.x=256 * BM=128), N = 512 (grid.y=4 * BN=128), K in {128,512}
// ---------------------------------------------------------------------------
__global__ __launch_bounds__(256) void gemm_bias_kernel(
    const float* __restrict__ A, const float* __restrict__ W,
    const float* __restrict__ b1, const float* __restrict__ b2,
    float* __restrict__ out, int K)
{
    __shared__ float As[16][132];
    __shared__ float Bs[16][132];
    const int tid = threadIdx.x;
    const int bm = blockIdx.x;
    const int bn = blockIdx.y;
    const int tx = tid & 15;
    const int ty = tid >> 4;
    const int lr = tid >> 2;
    const int lk = (tid & 3) << 2;

    const float* Ab = A + (size_t)bm * 128 * K;
    const float* Wb = W + (size_t)bn * 128 * K;

    float acc[8][8];
#pragma unroll
    for (int i = 0; i < 8; ++i)
#pragma unroll
        for (int j = 0; j < 8; ++j) acc[i][j] = 0.f;

    for (int k0 = 0; k0 < K; k0 += 16) {
        float4 a0 = *(const float4*)(Ab + (size_t)lr * K + k0 + lk);
        float4 a1 = *(const float4*)(Ab + (size_t)(lr + 64) * K + k0 + lk);
        float4 w0 = *(const float4*)(Wb + (size_t)lr * K + k0 + lk);
        float4 w1 = *(const float4*)(Wb + (size_t)(lr + 64) * K + k0 + lk);
        __syncthreads();
        As[lk + 0][lr] = a0.x; As[lk + 1][lr] = a0.y; As[lk + 2][lr] = a0.z; As[lk + 3][lr] = a0.w;
        As[lk + 0][lr + 64] = a1.x; As[lk + 1][lr + 64] = a1.y; As[lk + 2][lr + 64] = a1.z; As[lk + 3][lr + 64] = a1.w;
        Bs[lk + 0][lr] = w0.x; Bs[lk + 1][lr] = w0.y; Bs[lk + 2][lr] = w0.z; Bs[lk + 3][lr] = w0.w;
        Bs[lk + 0][lr + 64] = w1.x; Bs[lk + 1][lr + 64] = w1.y; Bs[lk + 2][lr + 64] = w1.z; Bs[lk + 3][lr + 64] = w1.w;
        __syncthreads();
#pragma unroll
        for (int k = 0; k < 16; ++k) {
            float4 av0 = *(const float4*)&As[k][ty * 8];
            float4 av1 = *(const float4*)&As[k][ty * 8 + 4];
            float4 bv0 = *(const float4*)&Bs[k][tx * 8];
            float4 bv1 = *(const float4*)&Bs[k][tx * 8 + 4];
            float a[8] = {av0.x, av0.y, av0.z, av0.w, av1.x, av1.y, av1.z, av1.w};
            float b[8] = {bv0.x, bv0.y, bv0.z, bv0.w, bv1.x, bv1.y, bv1.z, bv1.w};
#pragma unroll
            for (int i = 0; i < 8; ++i)
#pragma unroll
                for (int j = 0; j < 8; ++j)
                    acc[i][j] = fmaf(a[i], b[j], acc[i][j]);
        }
    }

    const int nb = bn * 128 + tx * 8;
    float bias[8];
#pragma unroll
    for (int j = 0; j < 8; ++j) bias[j] = b1[nb + j] + b2[nb + j];
#pragma unroll
    for (int i = 0; i < 8; ++i) {
        const size_t m = (size_t)bm * 128 + ty * 8 + i;
        float4 o0 = {acc[i][0] + bias[0], acc[i][1] + bias[1], acc[i][2] + bias[2], acc[i][3] + bias[3]};
        float4 o1 = {acc[i][4] + bias[4], acc[i][5] + bias[5], acc[i][6] + bias[6], acc[i][7] + bias[7]};
        *(float4*)(out + m * HH + nb) = o0;
        *(float4*)(out + m * HH + nb + 4) = o1;
    }
}

// ---------------------------------------------------------------------------
// Recurrent scan. 256 blocks x 512 threads. blockIdx = s*32 + g:
//   s = row-slice 0..7 (64 rows of W_hh), g = group 0..31 (batches 2g,2g+1).
// Group members share bx%8 -> same-XCD heuristic.
// W slice in VGPRs (64/thread; __launch_bounds__(512,2) caps occupancy so the
// allocator has 256 VGPRs -- R1's 52-VGPR spill killed residency).
// Exchange: wave 0 reduces+publishes payload, then ONE release atomicAdd on a
// per-group counter; all threads poll the single counter (target 8*(t+1)),
// then load the payload. 2 barriers/step.
// ---------------------------------------------------------------------------
__global__ __launch_bounds__(512, 2) void scan_kernel(
    const float* __restrict__ xp, const float* __restrict__ Whh,
    float* __restrict__ y, float* hbuf, int* counter)
{
    __shared__ float hb[2][2 * HH];      // [buf][batch*512]
    __shared__ float part[8][2][64];     // [k-wave][batch][row]

    const int tid  = threadIdx.x;
    const int s    = blockIdx.x >> 5;    // slice 0..7
    const int g    = blockIdx.x & 31;    // group 0..31
    const int lane = tid & 63;
    const int wv   = tid >> 6;           // wave 0..7 -> k-range [64*wv, 64*wv+64)

    // --- W slice resident in VGPRs for all 512 steps ---
    float wreg[64];
    {
        const float* wr = Whh + (size_t)(s * 64 + lane) * HH + wv * 64;
#pragma unroll
        for (int i = 0; i < 16; ++i) {
            float4 v = *(const float4*)(wr + 4 * i);
            wreg[4 * i] = v.x; wreg[4 * i + 1] = v.y; wreg[4 * i + 2] = v.z; wreg[4 * i + 3] = v.w;
        }
    }

    hb[0][tid] = 0.f;
    hb[0][tid + 512] = 0.f;

    const int gb0 = g * 2, gb1 = g * 2 + 1;
    float xp0 = 0.f, xp1 = 0.f;
    if (wv == 0) {
        xp0 = xp[(size_t)gb0 * TT * HH + s * 64 + lane];
        xp1 = xp[(size_t)gb1 * TT * HH + s * 64 + lane];
    }
    int* cnt = counter + g;
    __syncthreads();

    for (int t = 0; t < TT; ++t) {
        const int p = t & 1;

        // --- partial dot products: this wave's 64-wide k-slice, both batches ---
        float acc0 = 0.f, acc1 = 0.f;
        const float* h0p = &hb[p][wv * 64];
        const float* h1p = &hb[p][512 + wv * 64];
#pragma unroll
        for (int i = 0; i < 16; ++i) {
            float4 a = *(const float4*)(h0p + 4 * i);      // LDS broadcast
            float4 b = *(const float4*)(h1p + 4 * i);
            acc0 = fmaf(wreg[4 * i],     a.x, acc0);
            acc0 = fmaf(wreg[4 * i + 1], a.y, acc0);
            acc0 = fmaf(wreg[4 * i + 2], a.z, acc0);
            acc0 = fmaf(wreg[4 * i + 3], a.w, acc0);
            acc1 = fmaf(wreg[4 * i],     b.x, acc1);
            acc1 = fmaf(wreg[4 * i + 1], b.y, acc1);
            acc1 = fmaf(wreg[4 * i + 2], b.z, acc1);
            acc1 = fmaf(wreg[4 * i + 3], b.w, acc1);
        }
        part[wv][0][lane] = acc0;
        part[wv][1][lane] = acc1;
        __syncthreads();                                   // barrier A

        if (wv == 0) {
            float s0 = 0.f, s1 = 0.f;
#pragma unroll
            for (int w = 0; w < 8; ++w) { s0 += part[w][0][lane]; s1 += part[w][1][lane]; }
            const float hn0 = fmaxf(s0 + xp0, 0.f);
            const float hn1 = fmaxf(s1 + xp1, 0.f);
            if (t + 1 < TT) {
                // publish payload then release-add the counter (critical path)
                float* dst = hbuf + ((size_t)((t + 1) & 1) * 32 + g) * 1024 + s * 64 + lane;
                __hip_atomic_store(dst,       hn0, __ATOMIC_RELAXED, __HIP_MEMORY_SCOPE_AGENT);
                __hip_atomic_store(dst + 512, hn1, __ATOMIC_RELAXED, __HIP_MEMORY_SCOPE_AGENT);
                if (lane == 0)
                    __hip_atomic_fetch_add(cnt, 1, __ATOMIC_RELEASE, __HIP_MEMORY_SCOPE_AGENT);
            }
            // off critical path: layer output + next xp prefetch
            y[((size_t)gb0 * TT + t) * HH + s * 64 + lane] = hn0;
            y[((size_t)gb1 * TT + t) * HH + s * 64 + lane] = hn1;
            if (t + 1 < TT) {
                xp0 = xp[((size_t)gb0 * TT + t + 1) * HH + s * 64 + lane];
                xp1 = xp[((size_t)gb1 * TT + t + 1) * HH + s * 64 + lane];
            }
        }

        if (t + 1 < TT) {
            const int tgt = 8 * (t + 1);
            while (__hip_atomic_load(cnt, __ATOMIC_ACQUIRE, __HIP_MEMORY_SCOPE_AGENT) < tgt) { }
            float* src = hbuf + ((size_t)((t + 1) & 1) * 32 + g) * 1024;
            float v0 = __hip_atomic_load(src + tid,       __ATOMIC_RELAXED, __HIP_MEMORY_SCOPE_AGENT);
            float v1 = __hip_atomic_load(src + tid + 512, __ATOMIC_RELAXED, __HIP_MEMORY_SCOPE_AGENT);
            hb[p ^ 1][tid] = v0;
            hb[p ^ 1][tid + 512] = v1;
        }
        __syncthreads();                                   // barrier B
    }
}

// ---------------------------------------------------------------------------
// Head: out[b][c] = sum_h y[b][T-1][h] * W_out[c][h] + b_out[c]
// ---------------------------------------------------------------------------
__global__ __launch_bounds__(64) void head_kernel(
    const float* __restrict__ y2, const float* __restrict__ Wout,
    const float* __restrict__ bout, float* __restrict__ out)
{
    const int bc = blockIdx.x;
    const int b = bc / CC, c = bc % CC;
    const int lane = threadIdx.x;
    const float* yrow = y2 + ((size_t)b * TT + (TT - 1)) * HH;
    const float* wrow = Wout + (size_t)c * HH;
    float s = 0.f;
#pragma unroll
    for (int i = 0; i < HH / 64; ++i)
        s = fmaf(yrow[lane + 64 * i], wrow[lane + 64 * i], s);
#pragma unroll
    for (int off = 32; off > 0; off >>= 1) s += __shfl_down(s, off);
    if (lane == 0) out[bc] = s + bout[c];
}

// ---------------------------------------------------------------------------
extern "C" void kernel_launch(void* const* d_in, const int* in_sizes, int n_in,
                              void* d_out, int out_size, void* d_ws, size_t ws_size,
                              hipStream_t stream)
{
    const float* x = (const float*)d_in[0];
    const float* W_ih[3] = {(const float*)d_in[1], (const float*)d_in[5], (const float*)d_in[9]};
    const float* W_hh[3] = {(const float*)d_in[2], (const float*)d_in[6], (const float*)d_in[10]};
    const float* b_ih[3] = {(const float*)d_in[3], (const float*)d_in[7], (const float*)d_in[11]};
    const float* b_hh[3] = {(const float*)d_in[4], (const float*)d_in[8], (const float*)d_in[12]};
    const float* W_out = (const float*)d_in[13];
    const float* b_out = (const float*)d_in[14];
    float* out = (float*)d_out;

    // workspace layout (floats): Y, XP, hbuf, counters
    float* ws   = (float*)d_ws;
    float* Y    = ws;                        // B*T*H
    float* XP   = ws + (size_t)BB * TT * HH; // B*T*H
    float* hbuf = XP + (size_t)BB * TT * HH; // 2*32*2*512
    int*   counters = (int*)(hbuf + 2 * 32 * 2 * 512); // [3][32]

    hipMemsetAsync(counters, 0, 3 * 32 * sizeof(int), stream);

    const dim3 ggrid(256, 4, 1);
    // layer 0
    gemm_bias_kernel<<<ggrid, 256, 0, stream>>>(x, W_ih[0], b_ih[0], b_hh[0], XP, II);
    scan_kernel<<<256, 512, 0, stream>>>(XP, W_hh[0], Y, hbuf, counters + 0 * 32);
    // layer 1
    gemm_bias_kernel<<<ggrid, 256, 0, stream>>>(Y, W_ih[1], b_ih[1], b_hh[1], XP, HH);
    scan_kernel<<<256, 512, 0, stream>>>(XP, W_hh[1], Y, hbuf, counters + 1 * 32);
    // layer 2
    gemm_bias_kernel<<<ggrid, 256, 0, stream>>>(Y, W_ih[2], b_ih[2], b_hh[2], XP, HH);
    scan_kernel<<<256, 512, 0, stream>>>(XP, W_hh[2], Y, hbuf, counters + 2 * 32);
    // head
    head_kernel<<<BB * CC, 64, 0, stream>>>(Y, W_out, b_out, out);
}

// Round 3
// 2867.171 us; speedup vs baseline: 31.0279x; 31.0279x over previous
//
#include <hip/hip_runtime.h>

// Problem constants
#define BB 64       // batch
#define TT 512      // time steps
#define II 128      // input dim
#define HH 512      // hidden
#define CC 5        // out classes

// ---------------------------------------------------------------------------
// GEMM: out[m][n] = sum_k A[m][k] * W[n][k] + b1[n] + b2[n]
// M = 32768 (grid.x=256 * BM=128), N = 512 (grid.y=4 * BN=128), K in {128,512}
// ---------------------------------------------------------------------------
__global__ __launch_bounds__(256) void gemm_bias_kernel(
    const float* __restrict__ A, const float* __restrict__ W,
    const float* __restrict__ b1, const float* __restrict__ b2,
    float* __restrict__ out, int K)
{
    __shared__ float As[16][132];
    __shared__ float Bs[16][132];
    const int tid = threadIdx.x;
    const int bm = blockIdx.x;
    const int bn = blockIdx.y;
    const int tx = tid & 15;
    const int ty = tid >> 4;
    const int lr = tid >> 2;
    const int lk = (tid & 3) << 2;

    const float* Ab = A + (size_t)bm * 128 * K;
    const float* Wb = W + (size_t)bn * 128 * K;

    float acc[8][8];
#pragma unroll
    for (int i = 0; i < 8; ++i)
#pragma unroll
        for (int j = 0; j < 8; ++j) acc[i][j] = 0.f;

    for (int k0 = 0; k0 < K; k0 += 16) {
        float4 a0 = *(const float4*)(Ab + (size_t)lr * K + k0 + lk);
        float4 a1 = *(const float4*)(Ab + (size_t)(lr + 64) * K + k0 + lk);
        float4 w0 = *(const float4*)(Wb + (size_t)lr * K + k0 + lk);
        float4 w1 = *(const float4*)(Wb + (size_t)(lr + 64) * K + k0 + lk);
        __syncthreads();
        As[lk + 0][lr] = a0.x; As[lk + 1][lr] = a0.y; As[lk + 2][lr] = a0.z; As[lk + 3][lr] = a0.w;
        As[lk + 0][lr + 64] = a1.x; As[lk + 1][lr + 64] = a1.y; As[lk + 2][lr + 64] = a1.z; As[lk + 3][lr + 64] = a1.w;
        Bs[lk + 0][lr] = w0.x; Bs[lk + 1][lr] = w0.y; Bs[lk + 2][lr] = w0.z; Bs[lk + 3][lr] = w0.w;
        Bs[lk + 0][lr + 64] = w1.x; Bs[lk + 1][lr + 64] = w1.y; Bs[lk + 2][lr + 64] = w1.z; Bs[lk + 3][lr + 64] = w1.w;
        __syncthreads();
#pragma unroll
        for (int k = 0; k < 16; ++k) {
            float4 av0 = *(const float4*)&As[k][ty * 8];
            float4 av1 = *(const float4*)&As[k][ty * 8 + 4];
            float4 bv0 = *(const float4*)&Bs[k][tx * 8];
            float4 bv1 = *(const float4*)&Bs[k][tx * 8 + 4];
            float a[8] = {av0.x, av0.y, av0.z, av0.w, av1.x, av1.y, av1.z, av1.w};
            float b[8] = {bv0.x, bv0.y, bv0.z, bv0.w, bv1.x, bv1.y, bv1.z, bv1.w};
#pragma unroll
            for (int i = 0; i < 8; ++i)
#pragma unroll
                for (int j = 0; j < 8; ++j)
                    acc[i][j] = fmaf(a[i], b[j], acc[i][j]);
        }
    }

    const int nb = bn * 128 + tx * 8;
    float bias[8];
#pragma unroll
    for (int j = 0; j < 8; ++j) bias[j] = b1[nb + j] + b2[nb + j];
#pragma unroll
    for (int i = 0; i < 8; ++i) {
        const size_t m = (size_t)bm * 128 + ty * 8 + i;
        float4 o0 = {acc[i][0] + bias[0], acc[i][1] + bias[1], acc[i][2] + bias[2], acc[i][3] + bias[3]};
        float4 o1 = {acc[i][4] + bias[4], acc[i][5] + bias[5], acc[i][6] + bias[6], acc[i][7] + bias[7]};
        *(float4*)(out + m * HH + nb) = o0;
        *(float4*)(out + m * HH + nb + 4) = o1;
    }
}

// ---------------------------------------------------------------------------
// Recurrent scan. 256 blocks x 512 threads. blockIdx = s*32 + g:
//   s = row-slice 0..7 (64 rows of W_hh), g = group 0..31 (batches 2g,2g+1).
// W slice in 16 explicit float4 VGPR vars (no array -> no SROA gamble);
// amdgpu_waves_per_eu(2,2) gives the allocator a 256-VGPR budget.
// Exchange protocol ("payload is the flag"): h>=0 after ReLU, so the sign
// bit of each published word carries a phase bit ((q+1)>>1)&1 for packet q
// in slot q&1 (alternates per slot reuse). Relaxed agent-scope stores/loads:
// value+readiness travel in the same dword -> one coherent RT per step, no
// fences, no flags. Each thread polls ITS OWN word (7 pollers/word, spread
// over 32K addresses -> no same-address contention, unlike R2).
// Wave wv consumes exactly block wv's packet; the reducer wave is wave s
// (local chunk short-circuits through LDS). `part` double-buffered by t&1
// -> ONE __syncthreads per step.
// ---------------------------------------------------------------------------
__global__ __launch_bounds__(512)
__attribute__((amdgpu_waves_per_eu(2, 2)))
void scan_kernel(
    const float* __restrict__ xp, const float* __restrict__ Whh,
    float* __restrict__ y, unsigned int* hbuf)
{
    __shared__ float hb[2][2 * HH];        // [buf][batch*512]
    __shared__ float part[2][8][2][64];    // [buf][k-wave][batch][row]

    const int tid  = threadIdx.x;
    const int s    = blockIdx.x >> 5;      // slice 0..7
    const int g    = blockIdx.x & 31;      // group 0..31
    const int lane = tid & 63;
    const int wv   = tid >> 6;             // wave 0..7 -> k-chunk [64*wv, 64*wv+64)

    // --- W slice: 16 explicit float4 -> guaranteed VGPR residency ---
    const float* wr = Whh + (size_t)(s * 64 + lane) * HH + wv * 64;
    const float4 w0  = *(const float4*)(wr + 0);
    const float4 w1  = *(const float4*)(wr + 4);
    const float4 w2  = *(const float4*)(wr + 8);
    const float4 w3  = *(const float4*)(wr + 12);
    const float4 w4  = *(const float4*)(wr + 16);
    const float4 w5  = *(const float4*)(wr + 20);
    const float4 w6  = *(const float4*)(wr + 24);
    const float4 w7  = *(const float4*)(wr + 28);
    const float4 w8  = *(const float4*)(wr + 32);
    const float4 w9  = *(const float4*)(wr + 36);
    const float4 w10 = *(const float4*)(wr + 40);
    const float4 w11 = *(const float4*)(wr + 44);
    const float4 w12 = *(const float4*)(wr + 48);
    const float4 w13 = *(const float4*)(wr + 52);
    const float4 w14 = *(const float4*)(wr + 56);
    const float4 w15 = *(const float4*)(wr + 60);

    hb[0][tid] = 0.f;
    hb[0][tid + 512] = 0.f;

    unsigned int* gbase = hbuf + (size_t)g * 2048;   // [slot][1024 words]
    const int gb0 = g * 2, gb1 = g * 2 + 1;
    float xp0 = 0.f, xp1 = 0.f;
    if (wv == s) {
        xp0 = xp[(size_t)gb0 * TT * HH + s * 64 + lane];
        xp1 = xp[(size_t)gb1 * TT * HH + s * 64 + lane];
    }
    __syncthreads();

    for (int t = 0; t < TT; ++t) {
        const int p = t & 1;

        // --- partial dot products over this wave's 64-wide k-chunk ---
        float a0 = 0.f, a1 = 0.f, b0 = 0.f, b1 = 0.f;   // 2 chains/batch for ILP
        const float* h0p = &hb[p][wv * 64];
        const float* h1p = &hb[p][512 + wv * 64];
#define STEP4(WQ, OFF)                                                   \
        {                                                                \
            float4 h0 = *(const float4*)(h0p + (OFF));                   \
            float4 h1 = *(const float4*)(h1p + (OFF));                   \
            a0 = fmaf(WQ.x, h0.x, a0); a1 = fmaf(WQ.y, h0.y, a1);        \
            a0 = fmaf(WQ.z, h0.z, a0); a1 = fmaf(WQ.w, h0.w, a1);        \
            b0 = fmaf(WQ.x, h1.x, b0); b1 = fmaf(WQ.y, h1.y, b1);        \
            b0 = fmaf(WQ.z, h1.z, b0); b1 = fmaf(WQ.w, h1.w, b1);        \
        }
        STEP4(w0, 0)   STEP4(w1, 4)   STEP4(w2, 8)   STEP4(w3, 12)
        STEP4(w4, 16)  STEP4(w5, 20)  STEP4(w6, 24)  STEP4(w7, 28)
        STEP4(w8, 32)  STEP4(w9, 36)  STEP4(w10, 40) STEP4(w11, 44)
        STEP4(w12, 48) STEP4(w13, 52) STEP4(w14, 56) STEP4(w15, 60)
#undef STEP4
        part[p][wv][0][lane] = a0 + a1;
        part[p][wv][1][lane] = b0 + b1;
        __syncthreads();                               // the ONLY barrier/step

        const int q = t + 1;                           // packet index
        const int slot = q & 1;
        const unsigned int phase = (unsigned int)(((q + 1) >> 1) & 1);

        if (wv == s) {
            // reduce + activation
            float s0 = 0.f, s1 = 0.f;
#pragma unroll
            for (int w = 0; w < 8; ++w) {
                s0 += part[p][w][0][lane];
                s1 += part[p][w][1][lane];
            }
            const float hn0 = fmaxf(s0 + xp0, 0.f);
            const float hn1 = fmaxf(s1 + xp1, 0.f);
            if (q < TT) {
                unsigned int* dst = gbase + slot * 1024 + s * 64 + lane;
                __hip_atomic_store(dst, __float_as_uint(hn0) | (phase << 31),
                                   __ATOMIC_RELAXED, __HIP_MEMORY_SCOPE_AGENT);
                __hip_atomic_store(dst + 512, __float_as_uint(hn1) | (phase << 31),
                                   __ATOMIC_RELAXED, __HIP_MEMORY_SCOPE_AGENT);
            }
            // local short-circuit: own chunk for next step (same-wave LDS)
            hb[p ^ 1][s * 64 + lane] = hn0;
            hb[p ^ 1][512 + s * 64 + lane] = hn1;
            // off critical path: layer output + next xp
            y[((size_t)gb0 * TT + t) * HH + s * 64 + lane] = hn0;
            y[((size_t)gb1 * TT + t) * HH + s * 64 + lane] = hn1;
            if (q < TT) {
                xp0 = xp[((size_t)gb0 * TT + q) * HH + s * 64 + lane];
                xp1 = xp[((size_t)gb1 * TT + q) * HH + s * 64 + lane];
            }
        } else if (q < TT) {
            // consume block wv's packet: poll own word, payload==flag
            unsigned int* src = gbase + slot * 1024 + tid;   // row tid = wv*64+lane
            unsigned int u0, u1;
            for (;;) {
                u0 = __hip_atomic_load(src, __ATOMIC_RELAXED, __HIP_MEMORY_SCOPE_AGENT);
                u1 = __hip_atomic_load(src + 512, __ATOMIC_RELAXED, __HIP_MEMORY_SCOPE_AGENT);
                if (((u0 >> 31) == phase) && ((u1 >> 31) == phase)) break;
            }
            hb[p ^ 1][tid] = __uint_as_float(u0 & 0x7fffffffu);
            hb[p ^ 1][512 + tid] = __uint_as_float(u1 & 0x7fffffffu);
        }
    }
}

// ---------------------------------------------------------------------------
// Head: out[b][c] = sum_h y[b][T-1][h] * W_out[c][h] + b_out[c]
// ---------------------------------------------------------------------------
__global__ __launch_bounds__(64) void head_kernel(
    const float* __restrict__ y2, const float* __restrict__ Wout,
    const float* __restrict__ bout, float* __restrict__ out)
{
    const int bc = blockIdx.x;
    const int b = bc / CC, c = bc % CC;
    const int lane = threadIdx.x;
    const float* yrow = y2 + ((size_t)b * TT + (TT - 1)) * HH;
    const float* wrow = Wout + (size_t)c * HH;
    float s = 0.f;
#pragma unroll
    for (int i = 0; i < HH / 64; ++i)
        s = fmaf(yrow[lane + 64 * i], wrow[lane + 64 * i], s);
#pragma unroll
    for (int off = 32; off > 0; off >>= 1) s += __shfl_down(s, off);
    if (lane == 0) out[bc] = s + bout[c];
}

// ---------------------------------------------------------------------------
extern "C" void kernel_launch(void* const* d_in, const int* in_sizes, int n_in,
                              void* d_out, int out_size, void* d_ws, size_t ws_size,
                              hipStream_t stream)
{
    const float* x = (const float*)d_in[0];
    const float* W_ih[3] = {(const float*)d_in[1], (const float*)d_in[5], (const float*)d_in[9]};
    const float* W_hh[3] = {(const float*)d_in[2], (const float*)d_in[6], (const float*)d_in[10]};
    const float* b_ih[3] = {(const float*)d_in[3], (const float*)d_in[7], (const float*)d_in[11]};
    const float* b_hh[3] = {(const float*)d_in[4], (const float*)d_in[8], (const float*)d_in[12]};
    const float* W_out = (const float*)d_in[13];
    const float* b_out = (const float*)d_in[14];
    float* out = (float*)d_out;

    // workspace layout (floats): Y, XP, hbuf  (same footprint as passing R1)
    float* ws   = (float*)d_ws;
    float* Y    = ws;                        // B*T*H
    float* XP   = ws + (size_t)BB * TT * HH; // B*T*H
    unsigned int* hbuf = (unsigned int*)(XP + (size_t)BB * TT * HH); // 32 groups * 2 slots * 1024 words

    const size_t hbuf_bytes = 32 * 2 * 1024 * sizeof(unsigned int);  // 256 KB
    const dim3 ggrid(256, 4, 1);

    // layer 0
    gemm_bias_kernel<<<ggrid, 256, 0, stream>>>(x, W_ih[0], b_ih[0], b_hh[0], XP, II);
    hipMemsetAsync(hbuf, 0, hbuf_bytes, stream);     // phase-clean slate per layer
    scan_kernel<<<256, 512, 0, stream>>>(XP, W_hh[0], Y, hbuf);
    // layer 1
    gemm_bias_kernel<<<ggrid, 256, 0, stream>>>(Y, W_ih[1], b_ih[1], b_hh[1], XP, HH);
    hipMemsetAsync(hbuf, 0, hbuf_bytes, stream);
    scan_kernel<<<256, 512, 0, stream>>>(XP, W_hh[1], Y, hbuf);
    // layer 2
    gemm_bias_kernel<<<ggrid, 256, 0, stream>>>(Y, W_ih[2], b_ih[2], b_hh[2], XP, HH);
    hipMemsetAsync(hbuf, 0, hbuf_bytes, stream);
    scan_kernel<<<256, 512, 0, stream>>>(XP, W_hh[2], Y, hbuf);
    // head
    head_kernel<<<BB * CC, 64, 0, stream>>>(Y, W_out, b_out, out);
}

// Round 4
// 2723.006 us; speedup vs baseline: 32.6707x; 1.0529x over previous
//
#include <hip/hip_runtime.h>

// Problem constants
#define BB 64       // batch
#define TT 512      // time steps
#define II 128      // input dim
#define HH 512      // hidden
#define CC 5        // out classes

// ---------------------------------------------------------------------------
// GEMM: out[m][n] = sum_k A[m][k] * W[n][k] + b1[n] + b2[n]
// ---------------------------------------------------------------------------
__global__ __launch_bounds__(256) void gemm_bias_kernel(
    const float* __restrict__ A, const float* __restrict__ W,
    const float* __restrict__ b1, const float* __restrict__ b2,
    float* __restrict__ out, int K)
{
    __shared__ float As[16][132];
    __shared__ float Bs[16][132];
    const int tid = threadIdx.x;
    const int bm = blockIdx.x;
    const int bn = blockIdx.y;
    const int tx = tid & 15;
    const int ty = tid >> 4;
    const int lr = tid >> 2;
    const int lk = (tid & 3) << 2;

    const float* Ab = A + (size_t)bm * 128 * K;
    const float* Wb = W + (size_t)bn * 128 * K;

    float acc[8][8];
#pragma unroll
    for (int i = 0; i < 8; ++i)
#pragma unroll
        for (int j = 0; j < 8; ++j) acc[i][j] = 0.f;

    for (int k0 = 0; k0 < K; k0 += 16) {
        float4 a0 = *(const float4*)(Ab + (size_t)lr * K + k0 + lk);
        float4 a1 = *(const float4*)(Ab + (size_t)(lr + 64) * K + k0 + lk);
        float4 w0 = *(const float4*)(Wb + (size_t)lr * K + k0 + lk);
        float4 w1 = *(const float4*)(Wb + (size_t)(lr + 64) * K + k0 + lk);
        __syncthreads();
        As[lk + 0][lr] = a0.x; As[lk + 1][lr] = a0.y; As[lk + 2][lr] = a0.z; As[lk + 3][lr] = a0.w;
        As[lk + 0][lr + 64] = a1.x; As[lk + 1][lr + 64] = a1.y; As[lk + 2][lr + 64] = a1.z; As[lk + 3][lr + 64] = a1.w;
        Bs[lk + 0][lr] = w0.x; Bs[lk + 1][lr] = w0.y; Bs[lk + 2][lr] = w0.z; Bs[lk + 3][lr] = w0.w;
        Bs[lk + 0][lr + 64] = w1.x; Bs[lk + 1][lr + 64] = w1.y; Bs[lk + 2][lr + 64] = w1.z; Bs[lk + 3][lr + 64] = w1.w;
        __syncthreads();
#pragma unroll
        for (int k = 0; k < 16; ++k) {
            float4 av0 = *(const float4*)&As[k][ty * 8];
            float4 av1 = *(const float4*)&As[k][ty * 8 + 4];
            float4 bv0 = *(const float4*)&Bs[k][tx * 8];
            float4 bv1 = *(const float4*)&Bs[k][tx * 8 + 4];
            float a[8] = {av0.x, av0.y, av0.z, av0.w, av1.x, av1.y, av1.z, av1.w};
            float b[8] = {bv0.x, bv0.y, bv0.z, bv0.w, bv1.x, bv1.y, bv1.z, bv1.w};
#pragma unroll
            for (int i = 0; i < 8; ++i)
#pragma unroll
                for (int j = 0; j < 8; ++j)
                    acc[i][j] = fmaf(a[i], b[j], acc[i][j]);
        }
    }

    const int nb = bn * 128 + tx * 8;
    float bias[8];
#pragma unroll
    for (int j = 0; j < 8; ++j) bias[j] = b1[nb + j] + b2[nb + j];
#pragma unroll
    for (int i = 0; i < 8; ++i) {
        const size_t m = (size_t)bm * 128 + ty * 8 + i;
        float4 o0 = {acc[i][0] + bias[0], acc[i][1] + bias[1], acc[i][2] + bias[2], acc[i][3] + bias[3]};
        float4 o1 = {acc[i][4] + bias[4], acc[i][5] + bias[5], acc[i][6] + bias[6], acc[i][7] + bias[7]};
        *(float4*)(out + m * HH + nb) = o0;
        *(float4*)(out + m * HH + nb + 4) = o1;
    }
}

// ---------------------------------------------------------------------------
// Recurrent scan. 256 blocks x 512 threads. blockIdx = s*32 + g.
// R4 restructure vs R3:
//  - wave wv owns 8 FULL-K rows: lane = rloc*8 + kseg (rloc=lane>>3 local row,
//    kseg=lane&7 -> k-range kseg*64..+64). Complete dot product per wave via
//    3 shuffle-xor steps over kseg -- no cross-wave reduction, no part[] LDS,
//    and kseg==0 lanes publish DIRECTLY (all 8 waves publish in parallel).
//  - distributed poll (2 words/thread, R3-style) into ONE shared LDS h copy,
//    bank-padded [chunk][68]; ONE __syncthreads per step (was 2 + reduce hop).
// Protocol: payload-is-the-flag (sign bit = phase ((q+1)>>1)&1 of packet q in
// slot q&1), relaxed agent-scope ops; hbuf memset per layer keeps phases clean.
// ---------------------------------------------------------------------------
__global__ __launch_bounds__(512)
__attribute__((amdgpu_waves_per_eu(2, 2)))
void scan_kernel(
    const float* __restrict__ xp, const float* __restrict__ Whh,
    float* __restrict__ y, unsigned int* hbuf)
{
    __shared__ float hbs[2][2][8 * 68];   // [buf][batch][kseg*68 + m] (+4 pad/chunk)

    const int tid  = threadIdx.x;
    const int s    = blockIdx.x >> 5;      // slice 0..7 (rows s*64..s*64+63)
    const int g    = blockIdx.x & 31;      // group 0..31 (batches 2g, 2g+1)
    const int lane = tid & 63;
    const int wv   = tid >> 6;             // wave 0..7
    const int rloc = lane >> 3;            // 0..7: local row within wave
    const int kseg = lane & 7;             // 0..7: 64-wide k-segment
    const int R    = s * 64 + wv * 8 + rloc;   // global row this lane computes

    // --- W row R, k-range kseg*64..+64: 16 explicit float4 (VGPR-resident) ---
    const float* wr = Whh + (size_t)R * HH + kseg * 64;
    const float4 w0  = *(const float4*)(wr + 0);
    const float4 w1  = *(const float4*)(wr + 4);
    const float4 w2  = *(const float4*)(wr + 8);
    const float4 w3  = *(const float4*)(wr + 12);
    const float4 w4  = *(const float4*)(wr + 16);
    const float4 w5  = *(const float4*)(wr + 20);
    const float4 w6  = *(const float4*)(wr + 24);
    const float4 w7  = *(const float4*)(wr + 28);
    const float4 w8  = *(const float4*)(wr + 32);
    const float4 w9  = *(const float4*)(wr + 36);
    const float4 w10 = *(const float4*)(wr + 40);
    const float4 w11 = *(const float4*)(wr + 44);
    const float4 w12 = *(const float4*)(wr + 48);
    const float4 w13 = *(const float4*)(wr + 52);
    const float4 w14 = *(const float4*)(wr + 56);
    const float4 w15 = *(const float4*)(wr + 60);

    unsigned int* gbase = hbuf + (size_t)g * 2048;   // [slot][1024 words]
    const int gb0 = g * 2, gb1 = g * 2 + 1;

    // poll->LDS address for this thread's 2 words (h0[tid], h1[tid])
    const int lds_w = (tid >> 6) * 68 + (tid & 63);

    // init: packet 0 = zeros
    hbs[0][0][lds_w] = 0.f;
    hbs[0][1][lds_w] = 0.f;

    const bool pub = (kseg == 0);
    float xp0 = 0.f, xp1 = 0.f;
    if (pub) {
        xp0 = xp[(size_t)gb0 * TT * HH + R];
        xp1 = xp[(size_t)gb1 * TT * HH + R];
    }
    __syncthreads();

    for (int t = 0; t < TT; ++t) {
        const int p = t & 1;

        // --- full dot product for row R over this lane's k-segment ---
        float a0 = 0.f, a1 = 0.f, c0 = 0.f, c1 = 0.f;
        const float* h0p = &hbs[p][0][kseg * 68];
        const float* h1p = &hbs[p][1][kseg * 68];
#define STEP4(WQ, OFF)                                                   \
        {                                                                \
            float4 h0 = *(const float4*)(h0p + (OFF));                   \
            float4 h1 = *(const float4*)(h1p + (OFF));                   \
            a0 = fmaf(WQ.x, h0.x, a0); a1 = fmaf(WQ.y, h0.y, a1);        \
            a0 = fmaf(WQ.z, h0.z, a0); a1 = fmaf(WQ.w, h0.w, a1);        \
            c0 = fmaf(WQ.x, h1.x, c0); c1 = fmaf(WQ.y, h1.y, c1);        \
            c0 = fmaf(WQ.z, h1.z, c0); c1 = fmaf(WQ.w, h1.w, c1);        \
        }
        STEP4(w0, 0)   STEP4(w1, 4)   STEP4(w2, 8)   STEP4(w3, 12)
        STEP4(w4, 16)  STEP4(w5, 20)  STEP4(w6, 24)  STEP4(w7, 28)
        STEP4(w8, 32)  STEP4(w9, 36)  STEP4(w10, 40) STEP4(w11, 44)
        STEP4(w12, 48) STEP4(w13, 52) STEP4(w14, 56) STEP4(w15, 60)
#undef STEP4

        // --- butterfly reduce over kseg lanes (xor 1,2,4) ---
        float A = a0 + a1, Bv = c0 + c1;
        A  += __shfl_xor(A, 1);  A  += __shfl_xor(A, 2);  A  += __shfl_xor(A, 4);
        Bv += __shfl_xor(Bv, 1); Bv += __shfl_xor(Bv, 2); Bv += __shfl_xor(Bv, 4);

        const int q = t + 1;                           // packet index
        unsigned int* slotp = gbase + (q & 1) * 1024;
        const unsigned int phase = (unsigned int)(((q + 1) >> 1) & 1);

        if (pub) {
            const float hn0 = fmaxf(A + xp0, 0.f);
            const float hn1 = fmaxf(Bv + xp1, 0.f);
            if (q < TT) {
                __hip_atomic_store(slotp + R, __float_as_uint(hn0) | (phase << 31),
                                   __ATOMIC_RELAXED, __HIP_MEMORY_SCOPE_AGENT);
                __hip_atomic_store(slotp + 512 + R, __float_as_uint(hn1) | (phase << 31),
                                   __ATOMIC_RELAXED, __HIP_MEMORY_SCOPE_AGENT);
            }
            // off critical path
            y[((size_t)gb0 * TT + t) * HH + R] = hn0;
            y[((size_t)gb1 * TT + t) * HH + R] = hn1;
            if (q < TT) {
                xp0 = xp[((size_t)gb0 * TT + q) * HH + R];
                xp1 = xp[((size_t)gb1 * TT + q) * HH + R];
            }
        }

        if (q < TT) {
            // distributed poll: this thread's 2 words, payload==flag
            unsigned int* s0 = slotp + tid;
            unsigned int* s1 = slotp + 512 + tid;
            unsigned int u0, u1;
            for (;;) {
                u0 = __hip_atomic_load(s0, __ATOMIC_RELAXED, __HIP_MEMORY_SCOPE_AGENT);
                u1 = __hip_atomic_load(s1, __ATOMIC_RELAXED, __HIP_MEMORY_SCOPE_AGENT);
                if (((u0 >> 31) == phase) && ((u1 >> 31) == phase)) break;
            }
            hbs[q & 1][0][lds_w] = __uint_as_float(u0 & 0x7fffffffu);
            hbs[q & 1][1][lds_w] = __uint_as_float(u1 & 0x7fffffffu);
        }
        __syncthreads();                               // the ONLY barrier/step
    }
}

// ---------------------------------------------------------------------------
// Head: out[b][c] = sum_h y[b][T-1][h] * W_out[c][h] + b_out[c]
// ---------------------------------------------------------------------------
__global__ __launch_bounds__(64) void head_kernel(
    const float* __restrict__ y2, const float* __restrict__ Wout,
    const float* __restrict__ bout, float* __restrict__ out)
{
    const int bc = blockIdx.x;
    const int b = bc / CC, c = bc % CC;
    const int lane = threadIdx.x;
    const float* yrow = y2 + ((size_t)b * TT + (TT - 1)) * HH;
    const float* wrow = Wout + (size_t)c * HH;
    float s = 0.f;
#pragma unroll
    for (int i = 0; i < HH / 64; ++i)
        s = fmaf(yrow[lane + 64 * i], wrow[lane + 64 * i], s);
#pragma unroll
    for (int off = 32; off > 0; off >>= 1) s += __shfl_down(s, off);
    if (lane == 0) out[bc] = s + bout[c];
}

// ---------------------------------------------------------------------------
extern "C" void kernel_launch(void* const* d_in, const int* in_sizes, int n_in,
                              void* d_out, int out_size, void* d_ws, size_t ws_size,
                              hipStream_t stream)
{
    const float* x = (const float*)d_in[0];
    const float* W_ih[3] = {(const float*)d_in[1], (const float*)d_in[5], (const float*)d_in[9]};
    const float* W_hh[3] = {(const float*)d_in[2], (const float*)d_in[6], (const float*)d_in[10]};
    const float* b_ih[3] = {(const float*)d_in[3], (const float*)d_in[7], (const float*)d_in[11]};
    const float* b_hh[3] = {(const float*)d_in[4], (const float*)d_in[8], (const float*)d_in[12]};
    const float* W_out = (const float*)d_in[13];
    const float* b_out = (const float*)d_in[14];
    float* out = (float*)d_out;

    // workspace layout (floats): Y, XP, hbuf
    float* ws   = (float*)d_ws;
    float* Y    = ws;                        // B*T*H
    float* XP   = ws + (size_t)BB * TT * HH; // B*T*H
    unsigned int* hbuf = (unsigned int*)(XP + (size_t)BB * TT * HH); // 32*2*1024 words

    const size_t hbuf_bytes = 32 * 2 * 1024 * sizeof(unsigned int);  // 256 KB
    const dim3 ggrid(256, 4, 1);

    // layer 0
    gemm_bias_kernel<<<ggrid, 256, 0, stream>>>(x, W_ih[0], b_ih[0], b_hh[0], XP, II);
    hipMemsetAsync(hbuf, 0, hbuf_bytes, stream);     // phase-clean slate per layer
    scan_kernel<<<256, 512, 0, stream>>>(XP, W_hh[0], Y, hbuf);
    // layer 1
    gemm_bias_kernel<<<ggrid, 256, 0, stream>>>(Y, W_ih[1], b_ih[1], b_hh[1], XP, HH);
    hipMemsetAsync(hbuf, 0, hbuf_bytes, stream);
    scan_kernel<<<256, 512, 0, stream>>>(XP, W_hh[1], Y, hbuf);
    // layer 2
    gemm_bias_kernel<<<ggrid, 256, 0, stream>>>(Y, W_ih[2], b_ih[2], b_hh[2], XP, HH);
    hipMemsetAsync(hbuf, 0, hbuf_bytes, stream);
    scan_kernel<<<256, 512, 0, stream>>>(XP, W_hh[2], Y, hbuf);
    // head
    head_kernel<<<BB * CC, 64, 0, stream>>>(Y, W_out, b_out, out);
}